// Round 5
// baseline (190.795 us; speedup 1.0000x reference)
//
#include <hip/hip_runtime.h>
#include <math.h>

// ColumnBlockAttention via bf16 MFMA: b=16, t=8192, e=64, BLOCK=64, n_cols=128
// d_out = [out: b*t*64 f32 | A: b*t*128 f32].
//
// One workgroup (4 waves) per (batch b, row-block m):
//   stage Kc(bf16), VcT(bf16) -> GEMM1 Z=Q.Kc^T (mfma 16x16x32 bf16)
//   -> mask/exp/row-reduce -> Aw (normalized weights, bf16, ALIASES Kc)
//   -> A written from Aw (coalesced f32) -> GEMM2 out=Aw.Vc
//   -> OutLds round-trip (aliases Aw; wave-private rows) -> float4 stores.
// LDS: max(Kc 18432, Aw 17408, OutLds 17408) + VcT 17408 = 35840 B -> 4 blk/CU.
// Layouts (HW-verified m89/m120): A-frag A[m=lane&15][k=(lane>>4)*8+j],
// B-frag B[k][n]: n=lane&15, k=(lane>>4)*8+j; C/D col=lane&15,
// row=(lane>>4)*4+reg.

#define TSEQ 8192
#define EDIM 64
#define NCOL 128
#define NBATCH 16

typedef __attribute__((ext_vector_type(8))) short short8;
typedef __attribute__((ext_vector_type(4))) float f32x4;

__device__ __forceinline__ unsigned short f2bf(float f) {   // RTNE bf16
    unsigned int u = __float_as_uint(f);
    return (unsigned short)((u + 0x7fffu + ((u >> 16) & 1u)) >> 16);
}
__device__ __forceinline__ float bf2f(unsigned short h) {
    return __uint_as_float(((unsigned int)h) << 16);
}

__global__ __launch_bounds__(256, 4)
void cba_kernel(const float* __restrict__ Q,
                const float* __restrict__ K,
                const float* __restrict__ V,
                float* __restrict__ Out,
                float* __restrict__ A)
{
    // region0: Kc[128][72] (18432 B) / Aw[64][136] (17408 B) / OutLds[64][68] (17408 B)
    // region1: VcT[64][136] (17408 B)
    __shared__ __align__(16) unsigned char lds_raw[18432 + 17408];
    unsigned short (*Kc)[72]   = (unsigned short(*)[72])lds_raw;
    unsigned short (*Aw)[136]  = (unsigned short(*)[136])lds_raw;
    float          (*OutLds)[68] = (float(*)[68])lds_raw;
    unsigned short (*VcT)[136] = (unsigned short(*)[136])(lds_raw + 18432);

    const int tid  = threadIdx.x;
    const int lane = tid & 63;
    const int wid  = tid >> 6;                 // 0..3: rows [16w,16w+16)
    const int b    = blockIdx.x >> 7;
    const int m    = blockIdx.x & 127;

    const size_t rowbase = (size_t)b * TSEQ + ((size_t)m << 6);

    // ---- stage Kc (bf16) and VcT (bf16, transposed) ----
    {
        const int j = tid >> 1;                // column 0..127
        const int h = (tid & 1) << 5;          // dim half: 0 or 32
        const size_t src = ((size_t)b * TSEQ + (j * 64 + 63)) * EDIM + h;
        const float4* ks = (const float4*)(K + src);
        const float4* vs = (const float4*)(V + src);
        #pragma unroll
        for (int t = 0; t < 8; ++t) {
            float4 kf = ks[t];
            unsigned int p0 = (unsigned int)f2bf(kf.x) | ((unsigned int)f2bf(kf.y) << 16);
            unsigned int p1 = (unsigned int)f2bf(kf.z) | ((unsigned int)f2bf(kf.w) << 16);
            *(unsigned int*)&Kc[j][h + 4 * t]     = p0;
            *(unsigned int*)&Kc[j][h + 4 * t + 2] = p1;
        }
        #pragma unroll
        for (int t = 0; t < 8; ++t) {
            float4 vf = vs[t];
            VcT[h + 4 * t + 0][j] = f2bf(vf.x);
            VcT[h + 4 * t + 1][j] = f2bf(vf.y);
            VcT[h + 4 * t + 2][j] = f2bf(vf.z);
            VcT[h + 4 * t + 3][j] = f2bf(vf.w);
        }
    }

    // ---- Q fragments (direct from global, pre-scaled by 1/8) ----
    const int kq = (lane >> 4) << 3;           // 8-dim group base
    short8 qa[2];
    {
        const int qrow = (wid << 4) + (lane & 15);
        const float* qp = Q + (rowbase + qrow) * EDIM;
        #pragma unroll
        for (int s = 0; s < 2; ++s) {
            float4 f0 = *(const float4*)(qp + 32 * s + kq);
            float4 f1 = *(const float4*)(qp + 32 * s + kq + 4);
            short8 v;
            v[0] = (short)f2bf(f0.x * 0.125f); v[1] = (short)f2bf(f0.y * 0.125f);
            v[2] = (short)f2bf(f0.z * 0.125f); v[3] = (short)f2bf(f0.w * 0.125f);
            v[4] = (short)f2bf(f1.x * 0.125f); v[5] = (short)f2bf(f1.y * 0.125f);
            v[6] = (short)f2bf(f1.z * 0.125f); v[7] = (short)f2bf(f1.w * 0.125f);
            qa[s] = v;
        }
    }
    __syncthreads();                           // barrier 1: staging visible

    // ---- GEMM1: 8 col-tiles x 2 K-steps ----
    f32x4 acc[8];
    #pragma unroll
    for (int t = 0; t < 8; ++t) acc[t] = (f32x4)0.f;
    #pragma unroll
    for (int t = 0; t < 8; ++t) {
        const unsigned short* kr = &Kc[(t << 4) + (lane & 15)][0];
        short8 b0 = *(const short8*)(kr + kq);
        short8 b1 = *(const short8*)(kr + 32 + kq);
        acc[t] = __builtin_amdgcn_mfma_f32_16x16x32_bf16(qa[0], b0, acc[t], 0, 0, 0);
        acc[t] = __builtin_amdgcn_mfma_f32_16x16x32_bf16(qa[1], b1, acc[t], 0, 0, 0);
    }

    // ---- mask + exp + row sums (C layout: col=lane&15, row=(lane>>4)*4+reg) ----
    const int rb = (wid << 4) + ((lane >> 4) << 2);   // row of reg 0 (in 64-block)
    float rinv[4];
    #pragma unroll
    for (int reg = 0; reg < 4; ++reg) {
        const int r  = rb + reg;
        const int nv = m + (r == 63 ? 1 : 0);
        float sum = 0.f;
        #pragma unroll
        for (int t = 0; t < 8; ++t) {
            const int jc = (t << 4) + (lane & 15);
            float e = (jc < nv) ? __expf(acc[t][reg]) : 0.f;
            acc[t][reg] = e;
            sum += e;
        }
        sum += __shfl_xor(sum, 1); sum += __shfl_xor(sum, 2);
        sum += __shfl_xor(sum, 4); sum += __shfl_xor(sum, 8);
        rinv[reg] = (sum > 0.f) ? 1.0f / sum : 0.f;
    }

    __syncthreads();                           // barrier 2: Kc dead -> Aw may alias

    // ---- normalized weights -> Aw (bf16, aliases Kc) ----
    #pragma unroll
    for (int reg = 0; reg < 4; ++reg) {
        #pragma unroll
        for (int t = 0; t < 8; ++t)
            Aw[rb + reg][(t << 4) + (lane & 15)] = f2bf(acc[t][reg] * rinv[reg]);
    }
    __syncthreads();                           // barrier 3: Aw visible

    // ---- A output: coalesced f32 from Aw (wave w reads rows [16w,16w+16)) ----
    {
        const int row = tid >> 2;
        const int c0  = (tid & 3) << 5;            // 0,32,64,96
        const unsigned short* src = &Aw[row][c0];
        float4* dst = (float4*)(A + (rowbase + row) * NCOL + c0);
        #pragma unroll
        for (int g = 0; g < 4; ++g) {
            short8 u = *(const short8*)(src + 8 * g);
            float4 lo, hi;
            lo.x = bf2f((unsigned short)u[0]); lo.y = bf2f((unsigned short)u[1]);
            lo.z = bf2f((unsigned short)u[2]); lo.w = bf2f((unsigned short)u[3]);
            hi.x = bf2f((unsigned short)u[4]); hi.y = bf2f((unsigned short)u[5]);
            hi.z = bf2f((unsigned short)u[6]); hi.w = bf2f((unsigned short)u[7]);
            dst[2 * g] = lo; dst[2 * g + 1] = hi;
        }
    }

    // ---- GEMM2: out(64x64) = Aw(64x128) . Vc(128x64); 4 tiles x 4 K-steps ----
    short8 af[4];
    {
        const unsigned short* ar = &Aw[(wid << 4) + (lane & 15)][0];
        #pragma unroll
        for (int s = 0; s < 4; ++s) af[s] = *(const short8*)(ar + (s << 5) + kq);
    }
    f32x4 oacc[4];
    #pragma unroll
    for (int t = 0; t < 4; ++t) oacc[t] = (f32x4)0.f;
    #pragma unroll
    for (int t = 0; t < 4; ++t) {
        const unsigned short* vr = &VcT[(t << 4) + (lane & 15)][0];
        #pragma unroll
        for (int s = 0; s < 4; ++s) {
            short8 vb = *(const short8*)(vr + (s << 5) + kq);
            oacc[t] = __builtin_amdgcn_mfma_f32_16x16x32_bf16(af[s], vb, oacc[t], 0, 0, 0);
        }
    }

    // ---- Out epilogue: LDS round-trip (OutLds aliases Aw; after barrier 4,
    //      rows [16w,16w+16) are wave-private: written and read only by wave w) ----
    __syncthreads();                           // barrier 4: all Aw reads done
    #pragma unroll
    for (int t = 0; t < 4; ++t) {
        #pragma unroll
        for (int reg = 0; reg < 4; ++reg)
            OutLds[rb + reg][(t << 4) + (lane & 15)] = oacc[t][reg];
    }
    {
        const int r2 = lane >> 2;                  // 0..15
        const int c2 = lane & 3;                   // 0..3 (16-float chunk)
        const int row = (wid << 4) + r2;
        const float4* src = (const float4*)&OutLds[row][c2 << 4];
        float4* dst = (float4*)(Out + (rowbase + row) * EDIM + (c2 << 4));
        #pragma unroll
        for (int u = 0; u < 4; ++u) dst[u] = src[u];
    }
}

extern "C" void kernel_launch(void* const* d_in, const int* in_sizes, int n_in,
                              void* d_out, int out_size, void* d_ws, size_t ws_size,
                              hipStream_t stream) {
    const float* Q = (const float*)d_in[0];
    const float* K = (const float*)d_in[1];
    const float* V = (const float*)d_in[2];
    float* Out = (float*)d_out;
    float* A   = Out + (size_t)NBATCH * TSEQ * EDIM;

    // 2048 workgroups x 256 threads: one per (batch, row-block)
    cba_kernel<<<dim3(NBATCH * NCOL), dim3(256), 0, stream>>>(Q, K, V, Out, A);
}

// Round 6
// 172.442 us; speedup vs baseline: 1.1064x; 1.1064x over previous
//
#include <hip/hip_runtime.h>
#include <math.h>

// ColumnBlockAttention via bf16 MFMA: b=16, t=8192, e=64, BLOCK=64, n_cols=128
// d_out = [out: b*t*64 f32 | A: b*t*128 f32].
//
// One workgroup per (batch, group of MPG=4 m-blocks). Kc/VcT are per-batch
// constants -> staged ONCE; the wg loops over its 4 m-blocks:
//   convert prefetched Q -> GEMM1 Z=Q.Kc^T (mfma 16x16x32 bf16)
//   -> prefetch next Q -> mask/exp/row-reduce -> normalize in regs
//   -> A stored DIRECTLY from f32 accs (no LDS round-trip)
//   -> Aw(bf16) -> LDS (GEMM2 operand transpose only), 2 barriers
//   -> GEMM2 out=Aw.Vc -> Out stored directly from C-layout regs.
// Iterations pipeline: stores of iter i drain during compute of i+1.
// Layouts (HW-verified m89/m120): A-frag A[m=lane&15][k=(lane>>4)*8+j],
// B-frag B[k][n]: n=lane&15, k=(lane>>4)*8+j; C/D col=lane&15,
// row=(lane>>4)*4+reg.

#define TSEQ 8192
#define EDIM 64
#define NCOL 128
#define NBATCH 16
#define MPG 4            // m-blocks per workgroup

typedef __attribute__((ext_vector_type(8))) short short8;
typedef __attribute__((ext_vector_type(4))) float f32x4;

__device__ __forceinline__ unsigned short f2bf(float f) {   // RTNE bf16
    unsigned int u = __float_as_uint(f);
    return (unsigned short)((u + 0x7fffu + ((u >> 16) & 1u)) >> 16);
}

__global__ __launch_bounds__(256, 2)
void cba_kernel(const float* __restrict__ Q,
                const float* __restrict__ K,
                const float* __restrict__ V,
                float* __restrict__ Out,
                float* __restrict__ A)
{
    __shared__ unsigned short Kc[NCOL][72];    // Kc[col][dim]   (18432 B)
    __shared__ unsigned short VcT[EDIM][136];  // VcT[dim][col]  (17408 B)
    __shared__ unsigned short Aw[64][136];     // weights [row][col] (17408 B)

    const int tid  = threadIdx.x;
    const int lane = tid & 63;
    const int wid  = tid >> 6;                 // 0..3: rows [16w,16w+16)
    const int b    = blockIdx.x >> 5;          // 0..15
    const int mg   = blockIdx.x & 31;          // m-group: m = 4*mg + it

    const int c   = lane & 15;                 // col-in-tile / n index
    const int kq  = (lane >> 4) << 3;          // 8-dim k-group base
    const int rb  = (wid << 4) + ((lane >> 4) << 2);  // C-layout row base (in 64)
    const int qr  = (wid << 4) + c;            // A-frag row (in 64)

    // ---- prefetch Q for iteration 0 (issues before staging loads) ----
    float4 qf[4];
    {
        const int m0 = mg * MPG;
        const float* qp = Q + ((size_t)b * TSEQ + (m0 << 6) + qr) * EDIM;
        qf[0] = *(const float4*)(qp + kq);
        qf[1] = *(const float4*)(qp + kq + 4);
        qf[2] = *(const float4*)(qp + 32 + kq);
        qf[3] = *(const float4*)(qp + 32 + kq + 4);
    }

    // ---- stage Kc (bf16) and VcT (bf16, transposed) ONCE per workgroup ----
    {
        const int j = tid >> 1;                // column 0..127
        const int h = (tid & 1) << 5;          // dim half: 0 or 32
        const size_t src = ((size_t)b * TSEQ + (j * 64 + 63)) * EDIM + h;
        const float4* ks = (const float4*)(K + src);
        const float4* vs = (const float4*)(V + src);
        #pragma unroll
        for (int t = 0; t < 8; ++t) {
            float4 kf = ks[t];
            unsigned int p0 = (unsigned int)f2bf(kf.x) | ((unsigned int)f2bf(kf.y) << 16);
            unsigned int p1 = (unsigned int)f2bf(kf.z) | ((unsigned int)f2bf(kf.w) << 16);
            *(unsigned int*)&Kc[j][h + 4 * t]     = p0;
            *(unsigned int*)&Kc[j][h + 4 * t + 2] = p1;
        }
        #pragma unroll
        for (int t = 0; t < 8; ++t) {
            float4 vf = vs[t];
            VcT[h + 4 * t + 0][j] = f2bf(vf.x);
            VcT[h + 4 * t + 1][j] = f2bf(vf.y);
            VcT[h + 4 * t + 2][j] = f2bf(vf.z);
            VcT[h + 4 * t + 3][j] = f2bf(vf.w);
        }
    }
    __syncthreads();                           // staging visible (once)

    for (int it = 0; it < MPG; ++it) {
        const int m = mg * MPG + it;
        const size_t rowbase = (size_t)b * TSEQ + ((size_t)m << 6);

        // ---- convert prefetched Q (pre-scaled by 1/8) ----
        short8 qa[2];
        #pragma unroll
        for (int s = 0; s < 2; ++s) {
            float4 f0 = qf[2 * s], f1 = qf[2 * s + 1];
            short8 v;
            v[0] = (short)f2bf(f0.x * 0.125f); v[1] = (short)f2bf(f0.y * 0.125f);
            v[2] = (short)f2bf(f0.z * 0.125f); v[3] = (short)f2bf(f0.w * 0.125f);
            v[4] = (short)f2bf(f1.x * 0.125f); v[5] = (short)f2bf(f1.y * 0.125f);
            v[6] = (short)f2bf(f1.z * 0.125f); v[7] = (short)f2bf(f1.w * 0.125f);
            qa[s] = v;
        }

        // ---- GEMM1: 8 col-tiles x 2 K-steps ----
        f32x4 acc[8];
        #pragma unroll
        for (int t = 0; t < 8; ++t) acc[t] = (f32x4)0.f;
        #pragma unroll
        for (int t = 0; t < 8; ++t) {
            const unsigned short* kr = &Kc[(t << 4) + c][0];
            short8 b0 = *(const short8*)(kr + kq);
            short8 b1 = *(const short8*)(kr + 32 + kq);
            acc[t] = __builtin_amdgcn_mfma_f32_16x16x32_bf16(qa[0], b0, acc[t], 0, 0, 0);
            acc[t] = __builtin_amdgcn_mfma_f32_16x16x32_bf16(qa[1], b1, acc[t], 0, 0, 0);
        }

        // ---- prefetch Q for next iteration ----
        if (it + 1 < MPG) {
            const float* qp = Q + (rowbase + 64 + qr) * EDIM;
            qf[0] = *(const float4*)(qp + kq);
            qf[1] = *(const float4*)(qp + kq + 4);
            qf[2] = *(const float4*)(qp + 32 + kq);
            qf[3] = *(const float4*)(qp + 32 + kq + 4);
        }

        // ---- mask + exp + row sums; normalize in registers ----
        #pragma unroll
        for (int reg = 0; reg < 4; ++reg) {
            const int r  = rb + reg;
            const int nv = m + (r == 63 ? 1 : 0);
            float sum = 0.f;
            #pragma unroll
            for (int t = 0; t < 8; ++t) {
                const int jc = (t << 4) + c;
                float e = (jc < nv) ? __expf(acc[t][reg]) : 0.f;
                acc[t][reg] = e;
                sum += e;
            }
            sum += __shfl_xor(sum, 1); sum += __shfl_xor(sum, 2);
            sum += __shfl_xor(sum, 4); sum += __shfl_xor(sum, 8);
            const float rinv = (sum > 0.f) ? 1.0f / sum : 0.f;
            #pragma unroll
            for (int t = 0; t < 8; ++t) acc[t][reg] *= rinv;
        }

        // ---- A output: directly from f32 accumulators (C-layout) ----
        #pragma unroll
        for (int reg = 0; reg < 4; ++reg) {
            float* ap = A + (rowbase + rb + reg) * NCOL + c;
            #pragma unroll
            for (int t = 0; t < 8; ++t) ap[t << 4] = acc[t][reg];
        }

        __syncthreads();     // WAR: previous iteration's Aw readers done

        // ---- Aw (bf16) -> LDS, for GEMM2 operand transpose ----
        #pragma unroll
        for (int reg = 0; reg < 4; ++reg) {
            #pragma unroll
            for (int t = 0; t < 8; ++t)
                Aw[rb + reg][(t << 4) + c] = f2bf(acc[t][reg]);
        }
        __syncthreads();     // Aw visible

        // ---- GEMM2: out(64x64) = Aw(64x128) . Vc(128x64) ----
        short8 af[4];
        {
            const unsigned short* ar = &Aw[qr][0];
            #pragma unroll
            for (int s = 0; s < 4; ++s) af[s] = *(const short8*)(ar + (s << 5) + kq);
        }
        f32x4 oacc[4];
        #pragma unroll
        for (int t = 0; t < 4; ++t) oacc[t] = (f32x4)0.f;
        #pragma unroll
        for (int t = 0; t < 4; ++t) {
            const unsigned short* vr = &VcT[(t << 4) + c][0];
            #pragma unroll
            for (int s = 0; s < 4; ++s) {
                short8 vb = *(const short8*)(vr + (s << 5) + kq);
                oacc[t] = __builtin_amdgcn_mfma_f32_16x16x32_bf16(af[s], vb, oacc[t], 0, 0, 0);
            }
        }

        // ---- Out: directly from C-layout regs ----
        #pragma unroll
        for (int t = 0; t < 4; ++t) {
            #pragma unroll
            for (int reg = 0; reg < 4; ++reg)
                Out[(rowbase + rb + reg) * EDIM + (t << 4) + c] = oacc[t][reg];
        }
    }
}

extern "C" void kernel_launch(void* const* d_in, const int* in_sizes, int n_in,
                              void* d_out, int out_size, void* d_ws, size_t ws_size,
                              hipStream_t stream) {
    const float* Q = (const float*)d_in[0];
    const float* K = (const float*)d_in[1];
    const float* V = (const float*)d_in[2];
    float* Out = (float*)d_out;
    float* A   = Out + (size_t)NBATCH * TSEQ * EDIM;

    // 512 workgroups x 256 threads: one per (batch, 4 m-blocks); ~2 wgs/CU
    cba_kernel<<<dim3(NBATCH * 32), dim3(256), 0, stream>>>(Q, K, V, Out, A);
}